// Round 7
// baseline (162.935 us; speedup 1.0000x reference)
//
#include <hip/hip_runtime.h>
#include <hip/hip_fp16.h>

// Sinkhorn (B=64, R=1024, C=1024, fp32, TAU=1, MAX_ITER=10), linear space,
// fused row+col pairs. E[b][r][c] = exp(s) cached fp16 (512 row slots),
// zeroed for c >= nc. a[r] = exp(-u), cs[c] = column sums (3 rotating bufs).
//   pair kernel (one per iteration): block = (batch, 32-row chunk), 512 thr.
//     phase 1: 8 waves x 4 rows, 16 cols/lane -> row sums -> a_lds[32];
//              E chunk is staged into LDS fp16 [32][1024] (64 KiB) on the way.
//     phase 2: thread = 2 cols x 32 rows FROM LDS -> <=2 global atomicAdd.
//   XCD swizzle: bid&7 selects the batch OCTET (b>>3), so XCD k exclusively
//   processes batches 8k..8k+7 in every dispatch -> E stays in that XCD's
//   4 MiB L2 across all pairs and out_step (avg footprint ~3.9 MB/XCD).
// out = E * a[r] / cs_final[c] on valid region, else 0.

#define B_DIM 64
#define RCH 32

__device__ __forceinline__ float fast_rcp(float x) {
#if __has_builtin(__builtin_amdgcn_rcpf)
    return __builtin_amdgcn_rcpf(x);
#else
    return 1.0f / x;
#endif
}

__device__ __forceinline__ float wave_sum(float x) {
    #pragma unroll
    for (int off = 1; off < 64; off <<= 1) x += __shfl_xor(x, off);
    return x;
}

// Phase 2 (shared): column partial sums for this chunk from LDS -> atomics.
__device__ __forceinline__ void phase2_col(
    const __half* __restrict__ e_lds,     // [RCH][1024]
    const float* __restrict__ a_lds, int b, int nc, int t,
    float* __restrict__ cs_cur)
{
    const int c0 = t << 1;
    if (c0 >= nc) return;
    float s0 = 0.f, s1 = 0.f;
    #pragma unroll
    for (int rr = 0; rr < RCH; ++rr) {
        const float2 f = __half22float2(
            *reinterpret_cast<const __half2*>(e_lds + (rr << 10) + c0));
        const float av = a_lds[rr];          // broadcast; 0 for r >= nr
        s0 = fmaf(f.x, av, s0);
        s1 = fmaf(f.y, av, s1);
    }
    if (s0 != 0.f) atomicAdd(cs_cur + (b << 10) + c0, s0);
    if (s1 != 0.f) atomicAdd(cs_cur + (b << 10) + c0 + 1, s1);
}

// decode XCD-partitioned block id -> (b, rc): bid&7 = batch octet = b>>3.
__device__ __forceinline__ void decode_pair_bid(int bid, int& b, int& rc) {
    const int xcd = bid & 7;
    const int j = bid >> 3;        // 0..127
    rc = j & 15;
    b = (xcd << 3) | (j >> 4);
}

// Pair 0: reads s fp32, writes E = exp(s) (zero for c>=nc), stages LDS,
// row sums with w=1, col phase. Zeroes its slice of cs_next.
__global__ __launch_bounds__(512) void pair_first(
    const float* __restrict__ s, const int* __restrict__ nrows,
    const int* __restrict__ ncols, __half* __restrict__ E,
    float* __restrict__ a, float* __restrict__ cs_cur,
    float* __restrict__ cs_next)
{
    int b, rc;
    decode_pair_bid(blockIdx.x, b, rc);
    const int t = threadIdx.x;
    if (t < 64) cs_next[(b << 10) + (rc << 6) + t] = 0.f;

    const int nr = nrows[b];
    const int r0 = rc << 5;
    if (r0 >= nr) return;                 // uniform, before any barrier
    const int nc = ncols[b];

    __shared__ __half e_lds[RCH * 1024];  // 64 KiB
    __shared__ float a_lds[RCH];

    const int wave = t >> 6;
    const int lane = t & 63;
    const int cbase = lane << 4;          // 16 cols per lane
    const bool cOK = cbase < nc;

    #pragma unroll 1
    for (int k = 0; k < 4; ++k) {
        const int rr = (wave << 2) + k;   // 0..31
        const int r = r0 + rr;
        float sum = 0.f;
        __half2 h[8];
        if (r < nr && cOK) {
            const float* __restrict__ srow =
                s + ((size_t)b << 20) + ((size_t)r << 10) + cbase;
            float e[16];
            #pragma unroll
            for (int q = 0; q < 4; ++q) {
                const float4 x = *reinterpret_cast<const float4*>(srow + (q << 2));
                e[4 * q + 0] = __expf(x.x); e[4 * q + 1] = __expf(x.y);
                e[4 * q + 2] = __expf(x.z); e[4 * q + 3] = __expf(x.w);
            }
            #pragma unroll
            for (int j = 0; j < 16; ++j)
                if (cbase + j >= nc) e[j] = 0.f;
            #pragma unroll
            for (int q = 0; q < 8; ++q)
                h[q] = __floats2half2_rn(e[2 * q], e[2 * q + 1]);
            __half* __restrict__ erow =
                E + ((size_t)b << 19) + ((size_t)r << 10) + cbase;
            *reinterpret_cast<float4*>(erow)     = *reinterpret_cast<const float4*>(&h[0]);
            *reinterpret_cast<float4*>(erow + 8) = *reinterpret_cast<const float4*>(&h[4]);
            #pragma unroll
            for (int j = 0; j < 16; ++j) sum += e[j];
        } else {
            #pragma unroll
            for (int q = 0; q < 8; ++q) h[q] = __floats2half2_rn(0.f, 0.f);
        }
        // stage LDS (zeros for invalid rows/cols -> phase 2 needs no guards)
        __half* dst = e_lds + (rr << 10) + cbase;
        *reinterpret_cast<float4*>(dst)     = *reinterpret_cast<const float4*>(&h[0]);
        *reinterpret_cast<float4*>(dst + 8) = *reinterpret_cast<const float4*>(&h[4]);
        sum = wave_sum(sum);
        if (lane == 0) a_lds[rr] = (r < nr) ? 1.0f / sum : 0.f;
    }
    __syncthreads();
    if (t < RCH) a[(b << 9) + r0 + t] = a_lds[t];

    phase2_col(e_lds, a_lds, b, nc, t, cs_cur);
}

// Pairs 1..4: reads E (L2-resident), w = 1/cs_prev, stages LDS, col phase.
__global__ __launch_bounds__(512) void pair_mid(
    const __half* __restrict__ E, const int* __restrict__ nrows,
    const int* __restrict__ ncols, const float* __restrict__ cs_prev,
    float* __restrict__ a, float* __restrict__ cs_cur,
    float* __restrict__ cs_next)
{
    int b, rc;
    decode_pair_bid(blockIdx.x, b, rc);
    const int t = threadIdx.x;
    if (t < 64) cs_next[(b << 10) + (rc << 6) + t] = 0.f;

    const int nr = nrows[b];
    const int r0 = rc << 5;
    if (r0 >= nr) return;
    const int nc = ncols[b];

    __shared__ __half e_lds[RCH * 1024];
    __shared__ float a_lds[RCH];

    const int wave = t >> 6;
    const int lane = t & 63;
    const int cbase = lane << 4;
    const bool cOK = cbase < nc;

    float w[16];
    if (cOK) {
        const float* __restrict__ csp = cs_prev + (b << 10) + cbase;
        #pragma unroll
        for (int q = 0; q < 4; ++q) {
            const float4 c4 = *reinterpret_cast<const float4*>(csp + (q << 2));
            w[4 * q + 0] = (cbase + 4 * q + 0 < nc) ? fast_rcp(c4.x) : 0.f;
            w[4 * q + 1] = (cbase + 4 * q + 1 < nc) ? fast_rcp(c4.y) : 0.f;
            w[4 * q + 2] = (cbase + 4 * q + 2 < nc) ? fast_rcp(c4.z) : 0.f;
            w[4 * q + 3] = (cbase + 4 * q + 3 < nc) ? fast_rcp(c4.w) : 0.f;
        }
    }

    #pragma unroll 1
    for (int k = 0; k < 4; ++k) {
        const int rr = (wave << 2) + k;
        const int r = r0 + rr;
        float s0 = 0.f, s1 = 0.f;
        float4 p0, p1;
        if (r < nr && cOK) {
            const __half* __restrict__ erow =
                E + ((size_t)b << 19) + ((size_t)r << 10) + cbase;
            p0 = *reinterpret_cast<const float4*>(erow);
            p1 = *reinterpret_cast<const float4*>(erow + 8);
            const __half2* h0 = reinterpret_cast<const __half2*>(&p0);
            const __half2* h1 = reinterpret_cast<const __half2*>(&p1);
            #pragma unroll
            for (int q = 0; q < 4; ++q) {
                const float2 f = __half22float2(h0[q]);
                s0 = fmaf(f.x, w[2 * q], s0);
                s1 = fmaf(f.y, w[2 * q + 1], s1);
            }
            #pragma unroll
            for (int q = 0; q < 4; ++q) {
                const float2 f = __half22float2(h1[q]);
                s0 = fmaf(f.x, w[8 + 2 * q], s0);
                s1 = fmaf(f.y, w[8 + 2 * q + 1], s1);
            }
        } else {
            p0 = make_float4(0.f, 0.f, 0.f, 0.f);
            p1 = p0;
        }
        __half* dst = e_lds + (rr << 10) + cbase;
        *reinterpret_cast<float4*>(dst)     = p0;
        *reinterpret_cast<float4*>(dst + 8) = p1;
        const float sum = wave_sum(s0 + s1);
        if (lane == 0) a_lds[rr] = (r < nr) ? 1.0f / sum : 0.f;
    }
    __syncthreads();
    if (t < RCH) a[(b << 9) + r0 + t] = a_lds[t];

    phase2_col(e_lds, a_lds, b, nc, t, cs_cur);
}

// grid 65536 x 256. Block = one output row (b, r), XCD-partitioned like pairs.
__global__ __launch_bounds__(256) void out_step_f(
    const __half* __restrict__ E, const int* __restrict__ nrows,
    const int* __restrict__ ncols, const float* __restrict__ a,
    const float* __restrict__ cs, float* __restrict__ out)
{
    const int bid = blockIdx.x;
    const int xcd = bid & 7;
    const int j = bid >> 3;               // 0..8191
    const int r = j & 1023;
    const int b = (xcd << 3) | (j >> 10);
    const int c0 = threadIdx.x << 2;

    const int nr = nrows[b];
    const int nc = ncols[b];
    float4 o = make_float4(0.f, 0.f, 0.f, 0.f);
    if (r < nr && c0 < nc) {
        const float ar = a[(b << 9) + r];
        float2 pk = *reinterpret_cast<const float2*>(
            E + ((size_t)b << 19) + ((size_t)r << 10) + c0);
        const float2 f01 = __half22float2(reinterpret_cast<const __half2*>(&pk)[0]);
        const float2 f23 = __half22float2(reinterpret_cast<const __half2*>(&pk)[1]);
        const float4 c4 = *reinterpret_cast<const float4*>(cs + (b << 10) + c0);
        o.x = f01.x * ar * fast_rcp(c4.x);
        o.y = (c0 + 1 < nc) ? f01.y * ar * fast_rcp(c4.y) : 0.f;
        o.z = (c0 + 2 < nc) ? f23.x * ar * fast_rcp(c4.z) : 0.f;
        o.w = (c0 + 3 < nc) ? f23.y * ar * fast_rcp(c4.w) : 0.f;
    }
    *reinterpret_cast<float4*>(out + ((size_t)b << 20) + ((size_t)r << 10) + c0) = o;
}

// ==================== legacy path (small workspace) =========================

__global__ __launch_bounds__(256) void row_step_lg(
    const float* __restrict__ s, const int* __restrict__ nrows,
    const int* __restrict__ ncols, const float* __restrict__ vlog,
    const int use_v, float* __restrict__ u)
{
    const int b = blockIdx.y, r = blockIdx.x;
    const int nr = nrows[b];
    if (r >= nr) return;
    const int nc = ncols[b];
    const int t = threadIdx.x, c0 = t << 2;
    float sum = 0.f;
    if (c0 < nc) {
        const float4 x = reinterpret_cast<const float4*>(
            s + ((size_t)b << 20) + ((size_t)r << 10))[t];
        float4 vv = make_float4(0.f, 0.f, 0.f, 0.f);
        if (use_v) vv = reinterpret_cast<const float4*>(vlog + ((size_t)b << 10))[t];
        sum  = (c0 + 0 < nc) ? __expf(x.x - vv.x) : 0.f;
        sum += (c0 + 1 < nc) ? __expf(x.y - vv.y) : 0.f;
        sum += (c0 + 2 < nc) ? __expf(x.z - vv.z) : 0.f;
        sum += (c0 + 3 < nc) ? __expf(x.w - vv.w) : 0.f;
    }
    #pragma unroll
    for (int off = 1; off < 64; off <<= 1) sum += __shfl_xor(sum, off);
    __shared__ float ss[4];
    if ((t & 63) == 0) ss[t >> 6] = sum;
    __syncthreads();
    if (t == 0) u[((size_t)b << 9) + r] = __logf(ss[0] + ss[1] + ss[2] + ss[3]);
}

__global__ __launch_bounds__(256) void col_step_lg(
    const float* __restrict__ s, const int* __restrict__ nrows,
    const int* __restrict__ ncols, const float* __restrict__ u,
    float* __restrict__ partial)
{
    const int b = blockIdx.z, rc = blockIdx.y;
    const int nr = nrows[b];
    const int r0 = rc << 6;
    if (r0 >= nr) return;
    const int nc = ncols[b];
    const int c = (blockIdx.x << 8) + threadIdx.x;
    float sum = 0.f;
    if (c < nc) {
        const int rend = min(r0 + 64, nr);
        const float* __restrict__ sb = s + ((size_t)b << 20) + c;
        const float* __restrict__ ub = u + ((size_t)b << 9);
        float s0 = 0.f, s1 = 0.f, s2 = 0.f, s3 = 0.f;
        int r = r0;
        for (; r + 4 <= rend; r += 4) {
            s0 += __expf(sb[(size_t)(r + 0) << 10] - ub[r + 0]);
            s1 += __expf(sb[(size_t)(r + 1) << 10] - ub[r + 1]);
            s2 += __expf(sb[(size_t)(r + 2) << 10] - ub[r + 2]);
            s3 += __expf(sb[(size_t)(r + 3) << 10] - ub[r + 3]);
        }
        for (; r < rend; ++r) s0 += __expf(sb[(size_t)r << 10] - ub[r]);
        sum = (s0 + s1) + (s2 + s3);
    }
    partial[(((size_t)b << 3) + rc) << 10 | c] = sum;
}

__global__ __launch_bounds__(256) void col_fin_lg(
    const int* __restrict__ nrows, const float* __restrict__ partial,
    float* __restrict__ vlog)
{
    const int idx = (blockIdx.x << 8) + threadIdx.x;
    const int b = idx >> 10;
    const int nch = (nrows[b] + 63) >> 6;
    const float* __restrict__ p = partial + ((size_t)(b << 3) << 10) + (idx & 1023);
    float sum = 0.f;
    for (int k = 0; k < nch; ++k) sum += p[(size_t)k << 10];
    vlog[idx] = (sum > 0.f) ? __logf(sum) : 0.f;
}

__global__ __launch_bounds__(256) void out_step_lg(
    const float* __restrict__ s, const int* __restrict__ nrows,
    const int* __restrict__ ncols, const float* __restrict__ u,
    const float* __restrict__ vlog, float* __restrict__ out)
{
    const size_t total4 = (size_t)B_DIM * 1024 * 1024 / 4;
    float4* out4 = reinterpret_cast<float4*>(out);
    const float4* s4 = reinterpret_cast<const float4*>(s);
    for (size_t i = (size_t)blockIdx.x * blockDim.x + threadIdx.x; i < total4;
         i += (size_t)gridDim.x * blockDim.x) {
        const int b = (int)(i >> 18);
        const int rem = (int)(i & 262143);
        const int r = rem >> 8;
        const int c0 = (rem & 255) << 2;
        const int nr = nrows[b], nc = ncols[b];
        float4 o;
        if (r >= nr || c0 >= nc) {
            o = make_float4(0.f, 0.f, 0.f, 0.f);
        } else {
            float4 x = s4[i];
            const float ur = u[((size_t)b << 9) + r];
            const float* vb = vlog + ((size_t)b << 10);
            o.x = (c0 + 0 < nc) ? __expf(x.x - ur - vb[c0 + 0]) : 0.f;
            o.y = (c0 + 1 < nc) ? __expf(x.y - ur - vb[c0 + 1]) : 0.f;
            o.z = (c0 + 2 < nc) ? __expf(x.z - ur - vb[c0 + 2]) : 0.f;
            o.w = (c0 + 3 < nc) ? __expf(x.w - ur - vb[c0 + 3]) : 0.f;
        }
        out4[i] = o;
    }
}

// ============================================================================

extern "C" void kernel_launch(void* const* d_in, const int* in_sizes, int n_in,
                              void* d_out, int out_size, void* d_ws, size_t ws_size,
                              hipStream_t stream) {
    const float* s = (const float*)d_in[0];
    const int* nrows = (const int*)d_in[1];
    const int* ncols = (const int*)d_in[2];
    float* out = (float*)d_out;

    const size_t E_BYTES = (size_t)B_DIM * 512 * 1024 * 2;   // 64 MiB fp16
    const size_t CS_ELEMS = (size_t)B_DIM * 1024;
    const size_t NEED = E_BYTES + (size_t)B_DIM * 512 * 4 + 3 * CS_ELEMS * 4;

    if (ws_size >= NEED) {
        __half* E = (__half*)d_ws;
        float* a = (float*)((char*)d_ws + E_BYTES);
        float* cs0 = a + B_DIM * 512;
        float* cs1 = cs0 + CS_ELEMS;
        float* cs2 = cs1 + CS_ELEMS;

        hipMemsetAsync(cs0, 0, CS_ELEMS * sizeof(float), stream);

        const int nblk = 16 * B_DIM;  // 1024, XCD-partitioned decode in-kernel
        // pair i: prev=cs[(i+2)%3], cur=cs[i%3], next=cs[(i+1)%3]
        pair_first<<<nblk, 512, 0, stream>>>(s, nrows, ncols, E, a, cs0, cs1);
        pair_mid<<<nblk, 512, 0, stream>>>(E, nrows, ncols, cs0, a, cs1, cs2);
        pair_mid<<<nblk, 512, 0, stream>>>(E, nrows, ncols, cs1, a, cs2, cs0);
        pair_mid<<<nblk, 512, 0, stream>>>(E, nrows, ncols, cs2, a, cs0, cs1);
        pair_mid<<<nblk, 512, 0, stream>>>(E, nrows, ncols, cs0, a, cs1, cs2);
        out_step_f<<<65536, 256, 0, stream>>>(E, nrows, ncols, a, cs1, out);
    } else {
        // legacy log-space path (needs ~2.4 MiB)
        float* u = (float*)d_ws;
        float* vlog = u + (size_t)B_DIM * 512;
        float* partial = vlog + (size_t)B_DIM * 1024;
        const dim3 rowGrid(512, B_DIM);
        const dim3 colGrid(4, 8, B_DIM);
        for (int it = 0; it < 5; ++it) {
            row_step_lg<<<rowGrid, 256, 0, stream>>>(s, nrows, ncols, vlog, it, u);
            col_step_lg<<<colGrid, 256, 0, stream>>>(s, nrows, ncols, u, partial);
            col_fin_lg<<<256, 256, 0, stream>>>(nrows, partial, vlog);
        }
        out_step_lg<<<4096, 256, 0, stream>>>(s, nrows, ncols, u, vlog, out);
    }
}